// Round 8
// baseline (1782.220 us; speedup 1.0000x reference)
//
#include <hip/hip_runtime.h>
#include <stdint.h>

#define NQ 8192
#define NK 20000
#define RD 512
#define KN 256      // keys per tile (8 waves x 32 keys)
#define NTT 79      // ceil(20000/256); 79*256=20224, tail masked

typedef float f32x4 __attribute__((ext_vector_type(4)));
typedef short s16x8 __attribute__((ext_vector_type(8)));

__device__ __forceinline__ unsigned short bf16_rn(float x) {
    uint32_t u = __float_as_uint(x);
    return (unsigned short)((u + 0x7FFFu + ((u >> 16) & 1)) >> 16);
}

// barrier that waits ONLY on LDS ops -- global_load_lds queue stays in flight
__device__ __forceinline__ void lds_barrier() {
    asm volatile("s_waitcnt lgkmcnt(0)\n\ts_barrier" ::: "memory");
}
// ring waits: uniform schedule keeps 8 loads in flight, oldest 4 must land
__device__ __forceinline__ void wait_vm4() {
    asm volatile("s_waitcnt vmcnt(4)" ::: "memory");
}
// drain LDS pipe (ds_reads of current slots) before overwriting them
__device__ __forceinline__ void wait_lgkm0() {
    asm volatile("s_waitcnt lgkmcnt(0)" ::: "memory");
}

__device__ __forceinline__ void gload_lds16(const unsigned short* g, unsigned short* lds) {
    __builtin_amdgcn_global_load_lds(
        (const __attribute__((address_space(1))) uint32_t*)g,
        (__attribute__((address_space(3))) uint32_t*)lds, 16, 0, 0);
}

// ---------------- preconv: M(fp32) -> Mhi (RTZ hi), Mlo (RN residual), MT (RN bf16, transposed) ----
__global__ void preconv_kernel(const float* __restrict__ M,
                               unsigned short* __restrict__ Mhi,
                               unsigned short* __restrict__ Mlo,
                               unsigned short* __restrict__ MT) {
    __shared__ float tilef[64 * 65];
    const int k0 = blockIdx.x * 64, r0 = blockIdx.y * 64;
    const int t = threadIdx.x;
#pragma unroll
    for (int i = 0; i < 16; i++) {
        int e = t + i * 256;
        int kr = e >> 6, cc = e & 63;
        int key = k0 + kr;
        if (key < NK) {
            float x = M[(size_t)key * RD + r0 + cc];
            uint32_t u = __float_as_uint(x);
            Mhi[(size_t)key * RD + r0 + cc] = (unsigned short)(u >> 16);
            Mlo[(size_t)key * RD + r0 + cc] = bf16_rn(x - __uint_as_float(u & 0xFFFF0000u));
            tilef[cc * 65 + kr] = x;
        }
    }
    __syncthreads();
#pragma unroll
    for (int i = 0; i < 16; i++) {
        int e = t + i * 256;
        int rr = e >> 6, kk = e & 63;
        int key = k0 + kk;
        if (key < NK) MT[(size_t)(r0 + rr) * NK + key] = bf16_rn(tilef[rr * 65 + kk]);
    }
}

// ---------------- flash kernel v8: per-wave global_load_lds ring, manual vmcnt ----------------
// 512 thr = 8 waves, BM=32, KN=256. Wave w: S keys w*32..+31 (cb 0/1), both strips;
// PV cols w*64..+63. Per-wave 8-slot x 1KB LDS ring filled by global_load_lds (no VGPR
// dests -> compiler cannot sink the pipeline). Uniform schedule: 8 loads in flight,
// each step: wait vmcnt(4) -> ds_read own slots -> lgkmcnt(0) -> issue 4 more.
// Stream wraps: S steps 14/15 issue PV sk0/1; PV sk6/7 issue next tile ksteps 0/1.
// Barriers (softmax) are lgkm-only -> queue survives them.
__global__ __launch_bounds__(512, 2) void flash8_kernel(
        const float* __restrict__ h,
        const unsigned short* __restrict__ Mhi,
        const unsigned short* __restrict__ Mlo,
        const unsigned short* __restrict__ MT,
        float* __restrict__ out) {
    __shared__ unsigned short qbuf[32768];        // 64 KB: [hi|lo] x (2 strips x 16 steps) x 512 u16
    __shared__ unsigned short kring[8][8][512];   // 64 KB: [wave][slot][1KB frag]
    __shared__ unsigned short pbuf[16 * 512];     // 16 KB: P A-frags (sk*2 + strip)
    __shared__ float smaxb[8 * 2 * 16];           // [wave][strip][row16]
    __shared__ float ssumb[8 * 2 * 16];

    const int tid = threadIdx.x;
    const int w = tid >> 6, l = tid & 63;
    const int l15 = l & 15, q4 = l >> 4;
    const int kq = (l15 >> 3) & 1, jj = l15 & 7;
    const int qbase = blockIdx.x * 32;

    // ---- stage Q -> LDS (hi RTZ / lo RN), frag-linear ----
#pragma unroll
    for (int i = 0; i < 4; i++) {
        int g = tid + i * 512;                  // 0..2047 = row*64 + s*4 + qg
        int row = g >> 6, s = (g >> 2) & 15, qg = g & 3;
        int strip = row >> 4, lrow = row & 15;
        const float* src = h + (size_t)(qbase + row) * RD + s * 32 + qg * 8;
        f32x4 a = *(const f32x4*)src;
        f32x4 b = *(const f32x4*)(src + 4);
        s16x8 hi8, lo8;
#pragma unroll
        for (int j = 0; j < 8; j++) {
            float x = (j < 4) ? a[j] : b[j - 4];
            uint32_t u = __float_as_uint(x);
            hi8[j] = (short)(u >> 16);
            lo8[j] = (short)bf16_rn(x - __uint_as_float(u & 0xFFFF0000u));
        }
        int off = ((strip * 16 + s) * 512 + (qg * 16 + lrow) * 8);
        *(s16x8*)&qbuf[off] = hi8;
        *(s16x8*)&qbuf[16384 + off] = lo8;
    }

    // ---- issue helpers (all addresses per-lane; LDS dest wave-uniform + lane*16) ----
    const unsigned short* mtw = MT + (size_t)(w * 64 + l15) * NK + q4 * 8;
    auto issueK = [&](int t2, int s2) {         // 4 instr: khi cb0/cb1, klo cb0/cb1
        if (t2 >= NTT) t2 = NTT - 1;            // clamp: harmless reload, data unused
        int b = (s2 & 1) * 4;
        const size_t off = (size_t)(t2 * KN + w * 32 + l15) * RD + s2 * 32 + q4 * 8;
        gload_lds16(Mhi + off, &kring[w][b + 0][0]);
        gload_lds16(Mhi + off + (size_t)16 * RD, &kring[w][b + 1][0]);
        gload_lds16(Mlo + off, &kring[w][b + 2][0]);
        gload_lds16(Mlo + off + (size_t)16 * RD, &kring[w][b + 3][0]);
    };
    auto issuePV = [&](int t2, int sk2) {       // 4 instr: bt ct0..3 at keystep sk2
        int b = (sk2 & 1) * 4;
        const unsigned short* g = mtw + (size_t)t2 * KN + sk2 * 32;
#pragma unroll
        for (int ct = 0; ct < 4; ct++)
            gload_lds16(g + (size_t)ct * 16 * NK, &kring[w][b + ct][0]);
    };

    // prime: tile0 ksteps 0,1 (8 in flight)
    issueK(0, 0);
    issueK(0, 1);
    lds_barrier();      // qbuf visible; prime stays in flight

    f32x4 O[2][4];
#pragma unroll
    for (int st = 0; st < 2; st++)
#pragma unroll
        for (int ct = 0; ct < 4; ct++) O[st][ct] = 0.f;
    f32x4 m_run[2], l_run[2];
    m_run[0] = -3e38f; m_run[1] = -3e38f; l_run[0] = 0.f; l_run[1] = 0.f;

    for (int tile = 0; tile < NTT; tile++) {
        // ================= S phase =================
        f32x4 C[2][2];
        C[0][0] = 0.f; C[0][1] = 0.f; C[1][0] = 0.f; C[1][1] = 0.f;
#pragma unroll
        for (int s = 0; s < 16; s++) {
            wait_vm4();                          // kstep s landed (oldest 4 of 8)
            const int b = (s & 1) * 4;
            s16x8 kh0 = *(const s16x8*)&kring[w][b + 0][l * 8];
            s16x8 kh1 = *(const s16x8*)&kring[w][b + 1][l * 8];
            s16x8 kl0 = *(const s16x8*)&kring[w][b + 2][l * 8];
            s16x8 kl1 = *(const s16x8*)&kring[w][b + 3][l * 8];
            s16x8 qh0 = *(const s16x8*)&qbuf[s * 512 + l * 8];
            s16x8 ql0 = *(const s16x8*)&qbuf[16384 + s * 512 + l * 8];
            s16x8 qh1 = *(const s16x8*)&qbuf[(16 + s) * 512 + l * 8];
            s16x8 ql1 = *(const s16x8*)&qbuf[16384 + (16 + s) * 512 + l * 8];
            wait_lgkm0();                        // slots in regs -> safe to overwrite
            if (s < 14) issueK(tile, s + 2);
            else issuePV(tile, s - 14);          // s=14 -> sk0, s=15 -> sk1
            C[0][0] = __builtin_amdgcn_mfma_f32_16x16x32_bf16(qh0, kh0, C[0][0], 0, 0, 0);
            C[1][0] = __builtin_amdgcn_mfma_f32_16x16x32_bf16(qh1, kh0, C[1][0], 0, 0, 0);
            C[0][1] = __builtin_amdgcn_mfma_f32_16x16x32_bf16(qh0, kh1, C[0][1], 0, 0, 0);
            C[1][1] = __builtin_amdgcn_mfma_f32_16x16x32_bf16(qh1, kh1, C[1][1], 0, 0, 0);
            C[0][0] = __builtin_amdgcn_mfma_f32_16x16x32_bf16(ql0, kh0, C[0][0], 0, 0, 0);
            C[1][0] = __builtin_amdgcn_mfma_f32_16x16x32_bf16(ql1, kh0, C[1][0], 0, 0, 0);
            C[0][1] = __builtin_amdgcn_mfma_f32_16x16x32_bf16(ql0, kh1, C[0][1], 0, 0, 0);
            C[1][1] = __builtin_amdgcn_mfma_f32_16x16x32_bf16(ql1, kh1, C[1][1], 0, 0, 0);
            C[0][0] = __builtin_amdgcn_mfma_f32_16x16x32_bf16(qh0, kl0, C[0][0], 0, 0, 0);
            C[1][0] = __builtin_amdgcn_mfma_f32_16x16x32_bf16(qh1, kl0, C[1][0], 0, 0, 0);
            C[0][1] = __builtin_amdgcn_mfma_f32_16x16x32_bf16(qh0, kl1, C[0][1], 0, 0, 0);
            C[1][1] = __builtin_amdgcn_mfma_f32_16x16x32_bf16(qh1, kl1, C[1][1], 0, 0, 0);
        }
        // mask tail keys
        if (tile == NTT - 1) {
#pragma unroll
            for (int cb = 0; cb < 2; cb++) {
                int kg = tile * KN + w * 32 + cb * 16 + l15;
                if (kg >= NK) { C[0][cb] = -3e38f; C[1][cb] = -3e38f; }
            }
        }

        // ================= softmax (PV sk0/sk1 in flight throughout) =================
        f32x4 mx[2];
#pragma unroll
        for (int st = 0; st < 2; st++)
#pragma unroll
            for (int v = 0; v < 4; v++) mx[st][v] = fmaxf(C[st][0][v], C[st][1][v]);
#pragma unroll
        for (int d = 1; d < 16; d <<= 1) {
#pragma unroll
            for (int st = 0; st < 2; st++)
#pragma unroll
                for (int v = 0; v < 4; v++) mx[st][v] = fmaxf(mx[st][v], __shfl_xor(mx[st][v], d, 16));
        }
        if (l15 == 0) {
            *(f32x4*)&smaxb[(w * 2 + 0) * 16 + q4 * 4] = mx[0];
            *(f32x4*)&smaxb[(w * 2 + 1) * 16 + q4 * 4] = mx[1];
        }
        lds_barrier();   // B1
        f32x4 mnew[2]; mnew[0] = m_run[0]; mnew[1] = m_run[1];
#pragma unroll
        for (int cc = 0; cc < 8; cc++) {
#pragma unroll
            for (int st = 0; st < 2; st++) {
                f32x4 tv = *(const f32x4*)&smaxb[(cc * 2 + st) * 16 + q4 * 4];
#pragma unroll
                for (int v = 0; v < 4; v++) mnew[st][v] = fmaxf(mnew[st][v], tv[v]);
            }
        }
        f32x4 alpha[2];
#pragma unroll
        for (int st = 0; st < 2; st++)
#pragma unroll
            for (int v = 0; v < 4; v++) {
                alpha[st][v] = __expf(m_run[st][v] - mnew[st][v]);
                m_run[st][v] = mnew[st][v];
            }
        f32x4 ps[2]; ps[0] = 0.f; ps[1] = 0.f;
#pragma unroll
        for (int st = 0; st < 2; st++) {
#pragma unroll
            for (int cb = 0; cb < 2; cb++) {
#pragma unroll
                for (int v = 0; v < 4; v++) {
                    float p = __expf(C[st][cb][v] - mnew[st][v]);
                    ps[st][v] += p;
                    pbuf[(w * 2 + st) * 512 + ((cb * 2 + kq) * 16 + q4 * 4 + v) * 8 + jj] = bf16_rn(p);
                }
            }
        }
#pragma unroll
        for (int d = 1; d < 16; d <<= 1) {
#pragma unroll
            for (int st = 0; st < 2; st++)
#pragma unroll
                for (int v = 0; v < 4; v++) ps[st][v] += __shfl_xor(ps[st][v], d, 16);
        }
        if (l15 == 0) {
            *(f32x4*)&ssumb[(w * 2 + 0) * 16 + q4 * 4] = ps[0];
            *(f32x4*)&ssumb[(w * 2 + 1) * 16 + q4 * 4] = ps[1];
        }
        lds_barrier();   // B2 (pbuf + ssumb visible)
        f32x4 ts[2]; ts[0] = 0.f; ts[1] = 0.f;
#pragma unroll
        for (int cc = 0; cc < 8; cc++) {
            ts[0] += *(const f32x4*)&ssumb[(cc * 2 + 0) * 16 + q4 * 4];
            ts[1] += *(const f32x4*)&ssumb[(cc * 2 + 1) * 16 + q4 * 4];
        }
#pragma unroll
        for (int st = 0; st < 2; st++)
#pragma unroll
            for (int v = 0; v < 4; v++) l_run[st][v] = l_run[st][v] * alpha[st][v] + ts[st][v];
#pragma unroll
        for (int st = 0; st < 2; st++)
#pragma unroll
            for (int ct = 0; ct < 4; ct++)
#pragma unroll
                for (int v = 0; v < 4; v++) O[st][ct][v] *= alpha[st][v];

        // ================= PV phase (sk-outer; 8 steps) =================
#pragma unroll
        for (int sk = 0; sk < 8; sk++) {
            wait_vm4();                          // bt frags for sk landed
            const int b = (sk & 1) * 4;
            s16x8 bt0 = *(const s16x8*)&kring[w][b + 0][l * 8];
            s16x8 bt1 = *(const s16x8*)&kring[w][b + 1][l * 8];
            s16x8 bt2 = *(const s16x8*)&kring[w][b + 2][l * 8];
            s16x8 bt3 = *(const s16x8*)&kring[w][b + 3][l * 8];
            s16x8 pa0 = *(const s16x8*)&pbuf[(sk * 2 + 0) * 512 + l * 8];
            s16x8 pa1 = *(const s16x8*)&pbuf[(sk * 2 + 1) * 512 + l * 8];
            wait_lgkm0();                        // slots in regs -> safe to overwrite
            if (sk < 6) issuePV(tile, sk + 2);
            else issueK(tile + 1, sk - 6);       // sk=6 -> next kstep0, sk=7 -> kstep1
            O[0][0] = __builtin_amdgcn_mfma_f32_16x16x32_bf16(pa0, bt0, O[0][0], 0, 0, 0);
            O[1][0] = __builtin_amdgcn_mfma_f32_16x16x32_bf16(pa1, bt0, O[1][0], 0, 0, 0);
            O[0][1] = __builtin_amdgcn_mfma_f32_16x16x32_bf16(pa0, bt1, O[0][1], 0, 0, 0);
            O[1][1] = __builtin_amdgcn_mfma_f32_16x16x32_bf16(pa1, bt1, O[1][1], 0, 0, 0);
            O[0][2] = __builtin_amdgcn_mfma_f32_16x16x32_bf16(pa0, bt2, O[0][2], 0, 0, 0);
            O[1][2] = __builtin_amdgcn_mfma_f32_16x16x32_bf16(pa1, bt2, O[1][2], 0, 0, 0);
            O[0][3] = __builtin_amdgcn_mfma_f32_16x16x32_bf16(pa0, bt3, O[0][3], 0, 0, 0);
            O[1][3] = __builtin_amdgcn_mfma_f32_16x16x32_bf16(pa1, bt3, O[1][3], 0, 0, 0);
        }
        lds_barrier();   // pbuf consumed by all waves before next tile overwrites
    }

    // ================= epilogue =================
#pragma unroll
    for (int st = 0; st < 2; st++)
#pragma unroll
        for (int ct = 0; ct < 4; ct++)
#pragma unroll
            for (int v = 0; v < 4; v++)
                out[(size_t)(qbase + st * 16 + q4 * 4 + v) * RD + w * 64 + ct * 16 + l15] =
                    O[st][ct][v] / l_run[st][v];
}

// ---------------- fallback (ws too small): fp32, slow but exact ----------------
__global__ __launch_bounds__(256) void naive_kernel(const float* __restrict__ h,
                                                    const float* __restrict__ M,
                                                    float* __restrict__ out) {
    __shared__ float hs[16 * 520];
    __shared__ float ms[8 * 520];
    __shared__ float sdot[2][128];
    __shared__ float sm[16], sl[16], sal[16], sp[16][8];
    const int t = threadIdx.x;
    const int qbase = blockIdx.x * 16;
#pragma unroll
    for (int i = 0; i < 32; i++) {
        int e = t + i * 256;
        int row = e >> 9, col = e & 511;
        hs[row * 520 + col] = h[(size_t)(qbase + row) * RD + col];
    }
    if (t < 16) { sm[t] = -3e38f; sl[t] = 0.f; }
    float Oacc[32];
#pragma unroll
    for (int i = 0; i < 32; i++) Oacc[i] = 0.f;
    const int q = t >> 4;
    const int eb = (t & 15) * 32;

    for (int k0 = 0; k0 < NK; k0 += 8) {
        __syncthreads();
#pragma unroll
        for (int i = 0; i < 16; i++) {
            int e = t + i * 256;
            if (e < 4096) {
                int kk = e >> 9, col = e & 511;
                ms[kk * 520 + col] = M[(size_t)(k0 + kk) * RD + col];
            }
        }
        __syncthreads();
        {
            int pair = t & 127, half = t >> 7;
            int qq = pair & 15, kk = pair >> 4;
            const float* hp = &hs[qq * 520 + half * 256];
            const float* mp = &ms[kk * 520 + half * 256];
            float acc = 0.f;
#pragma unroll 8
            for (int e = 0; e < 256; e++) acc += hp[e] * mp[e];
            sdot[half][pair] = acc;
        }
        __syncthreads();
        if (t < 16) {
            int qq = t;
            float s8[8];
#pragma unroll
            for (int kk = 0; kk < 8; kk++) s8[kk] = sdot[0][qq + 16 * kk] + sdot[1][qq + 16 * kk];
            float mn = sm[qq];
#pragma unroll
            for (int kk = 0; kk < 8; kk++) mn = fmaxf(mn, s8[kk]);
            float al = __expf(sm[qq] - mn);
            float addl = 0.f;
#pragma unroll
            for (int kk = 0; kk < 8; kk++) { float p = __expf(s8[kk] - mn); sp[qq][kk] = p; addl += p; }
            sm[qq] = mn; sl[qq] = sl[qq] * al + addl; sal[qq] = al;
        }
        __syncthreads();
        {
            float al = sal[q];
#pragma unroll
            for (int i = 0; i < 32; i++) Oacc[i] *= al;
#pragma unroll
            for (int kk = 0; kk < 8; kk++) {
                float p = sp[q][kk];
                const float* mp = &ms[kk * 520 + eb];
#pragma unroll
                for (int i = 0; i < 32; i++) Oacc[i] += p * mp[i];
            }
        }
    }
    __syncthreads();
    float inv = 1.f / sl[q];
#pragma unroll
    for (int i = 0; i < 32; i++) out[(size_t)(qbase + q) * RD + eb + i] = Oacc[i] * inv;
}

extern "C" void kernel_launch(void* const* d_in, const int* in_sizes, int n_in,
                              void* d_out, int out_size, void* d_ws, size_t ws_size,
                              hipStream_t stream) {
    const float* h = (const float*)d_in[0];
    const float* M = (const float*)d_in[1];
    float* out = (float*)d_out;
    const size_t seg = (size_t)NK * RD;                      // u16 elems per converted buffer
    // Mhi + Mlo + MT + 8K u16 pad (tail reads stay in d_ws; 0xAA poison = finite bf16)
    const size_t need = (seg * 3ull + 8192ull) * 2ull;

    if (ws_size >= need) {
        unsigned short* Mhi = (unsigned short*)d_ws;
        unsigned short* Mlo = Mhi + seg;
        unsigned short* MT  = Mlo + seg;
        preconv_kernel<<<dim3(313, 8), 256, 0, stream>>>(M, Mhi, Mlo, MT);
        flash8_kernel<<<256, 512, 0, stream>>>(h, Mhi, Mlo, MT, out);
    } else {
        naive_kernel<<<512, 256, 0, stream>>>(h, M, out);
    }
}